// Round 1
// 145.802 us; speedup vs baseline: 1.1490x; 1.1490x over previous
//
#include <hip/hip_runtime.h>
#include <hip/hip_fp16.h>

#define N    4096
#define SIZE 128
#define CAP  128   // max stored neighbors per row (mean ~21.5), multiple of 8
#define RB   16    // output rows per block (one 16-row MFMA M-tile)
#define TB   1024  // threads per block (fused kernel)

typedef __attribute__((ext_vector_type(8))) _Float16 f16x8;  // MFMA A/B frag (4 VGPRs)
typedef __attribute__((ext_vector_type(2))) __fp16 fp16x2;   // cvt_pkrtz return type
typedef __attribute__((ext_vector_type(4))) float f32x4;     // MFMA C/D frag

__device__ __forceinline__ unsigned int pk2(float lo, float hi) {
    union { fp16x2 v; unsigned int u; } c;
    c.v = __builtin_amdgcn_cvt_pkrtz(lo, hi);   // 1 instr, RTZ
    return c.u;
}
__device__ __forceinline__ __half2 u2h(unsigned int u) {
    union { unsigned int u; __half2 h; } c; c.u = u; return c.h;
}

// ---- setup: blocks [0,N) build padded CSR rows; blocks [N,N+256) prep MFMA frags ----
// CSR build: per-thread 16-bit nonzero mask + wave shfl-scan + per-wave LDS total.
// No shared atomics, no serialized ballot rounds (old version: 16 dependent
// ballot->atomic->shfl rounds per block = long unhidden chain).
__global__ __launch_bounds__(256)
void setup(const float* __restrict__ nb, const float* __restrict__ f,
           const float* __restrict__ wq, const float* __restrict__ wk,
           int* __restrict__ cnt8, int* __restrict__ idx,
           _Float16* __restrict__ Af, _Float16* __restrict__ Bf) {
    __shared__ int   wtot[4];
    __shared__ float sf[SIZE][16];
    __shared__ float sqw[SIZE];
    const int t = threadIdx.x;

    if (blockIdx.x < N) {
        // ---------------- CSR build ----------------
        const int j    = blockIdx.x;
        const int lane = t & 63;
        const int wv   = t >> 6;
        const float4* row4 = (const float4*)(nb + (size_t)j * N);
        int* irow = idx + (size_t)j * CAP;

        float4 v[4];
#pragma unroll
        for (int it = 0; it < 4; ++it) v[it] = row4[t + it * 256];

        unsigned int msk = 0u;            // bit (it*4+q) = nz of col 4*(t+it*256)+q
#pragma unroll
        for (int it = 0; it < 4; ++it) {
            const float e[4] = {v[it].x, v[it].y, v[it].z, v[it].w};
#pragma unroll
            for (int q = 0; q < 4; ++q)
                if (e[q] != 0.0f) msk |= 1u << (it * 4 + q);
        }
        const int cnt = __popc(msk);
        int scan = cnt;                   // wave inclusive prefix sum (6 shfl steps)
#pragma unroll
        for (int s = 1; s < 64; s <<= 1) {
            const int o = __shfl_up(scan, s);
            if (lane >= s) scan += o;
        }
        if (lane == 63) wtot[wv] = scan;  // wave total
        __syncthreads();
        int base = 0;
#pragma unroll
        for (int w = 0; w < 3; ++w)
            if (w < wv) base += wtot[w];
        int p = base + scan - cnt;        // this thread's exclusive offset
        unsigned int m = msk;
        while (m) {                       // avg 0.08 nonzeros/thread
            const int b = __ffs(m) - 1;
            m &= m - 1u;
            const int c = 4 * (t + (b >> 2) * 256) + (b & 3);
            if (p < CAP) irow[p] = c;
            ++p;
        }
        if (t == 255) {                   // wv=3, lane=63: base+scan = row total
            int n = base + scan;
            if (n > CAP) n = CAP;
            const int n8 = (n + 7) & ~7;  // pad to 8 with sentinel -> zero LDS slot
            for (int q = n; q < n8; ++q) irow[q] = N;
            cnt8[j] = n8 >> 3;
        }
    } else {
        // ---------------- fragment prep (mapping unchanged, verified) ----------------
        const int tile = blockIdx.x - N;
        if (t < SIZE) sqw[t] = wq[t] * wk[t];
        const int col0 = t & 15;
#pragma unroll
        for (int it = 0; it < 8; ++it) {
            const int k = (t >> 4) + it * 16;
            sf[k][col0] = f[(size_t)k * N + tile * 16 + col0];
        }
        __syncthreads();
        const int ks   = t >> 6;
        const int lane = t & 63;
        const int quad = lane >> 4;
        const int col  = lane & 15;
        f16x8 va, vb;
#pragma unroll
        for (int jj = 0; jj < 8; ++jj) {
            const int k = ks * 32 + quad * 8 + jj;
            const float v = sf[k][col];
            va[jj] = (_Float16)(sqw[k] * v);
            vb[jj] = (_Float16)v;
        }
        const size_t o = (size_t)(tile * 4 + ks) * 64 + lane;
        ((f16x8*)Af)[o] = va;
        ((f16x8*)Bf)[o] = vb;
    }
}

// ---- fused kernel: 16 output rows per block via f16 MFMA + packed-f16 gather ----
__global__ __launch_bounds__(TB, 4)
void fused(const _Float16* __restrict__ Af, const _Float16* __restrict__ Bf,
           const int* __restrict__ cnt8, const int* __restrict__ idx,
           float* __restrict__ out) {
    // sA: rows 0-7 (8 f16/column), sB: rows 8-15; sB offset +2 slots; +1 slot each
    // is the zeroed sentinel (index N).
    __shared__ uint4 Sb[2 * N + 3];           // 131,120 B -> 1 block/CU (structural)
    uint4* const sA = Sb;
    uint4* const sB = Sb + N + 2;
    const int t    = threadIdx.x;
    const int lane = t & 63;
    const int wv   = t >> 6;
    const int quad = lane >> 4;
    const int i0   = blockIdx.x * RB;

    if (t == 0) {
        sA[N] = make_uint4(0u, 0u, 0u, 0u);
        sB[N] = make_uint4(0u, 0u, 0u, 0u);
    }

    // prefetch u=0 gather metadata BEFORE phase 1 + barrier (hides L2 latency)
    int cc = cnt8[t];
    const int4* ir0 = (const int4*)(idx + (size_t)t * CAP);
    int4 ka = ir0[0];
    int4 kb = ir0[1];

    // ---- phase 1 ----
    f16x8 af[4];
    const f16x8* Ap = (const f16x8*)Af + (size_t)blockIdx.x * 4 * 64;
#pragma unroll
    for (int ks = 0; ks < 4; ++ks) af[ks] = Ap[ks * 64 + lane];
    const f16x8* Bp = (const f16x8*)Bf;

#pragma unroll 4
    for (int ti = 0; ti < 16; ++ti) {
        const int nt = wv * 16 + ti;          // column tile: j = nt*16 .. nt*16+15
        f32x4 acc = {0.f, 0.f, 0.f, 0.f};
#pragma unroll
        for (int ks = 0; ks < 4; ++ks) {
            const f16x8 bfrag = Bp[(size_t)(nt * 4 + ks) * 64 + lane];
            acc = __builtin_amdgcn_mfma_f32_16x16x32_f16(af[ks], bfrag, acc, 0, 0, 0);
        }
        // C/D: col = lane&15, row = quad*4 + reg
        const int j = nt * 16 + (lane & 15);
        uint2 pp;
        pp.x = pk2(__expf(acc[0]), __expf(acc[1]));
        pp.y = pk2(__expf(acc[2]), __expf(acc[3]));
        uint2* bs = (quad < 2) ? (uint2*)&sA[j] : (uint2*)&sB[j];
        bs[quad & 1] = pp;
    }
    __syncthreads();

#define ACC(D, A, B) \
    D[0] = __hadd2(D[0], u2h((A).x)); D[1] = __hadd2(D[1], u2h((A).y)); \
    D[2] = __hadd2(D[2], u2h((A).z)); D[3] = __hadd2(D[3], u2h((A).w)); \
    D[4] = __hadd2(D[4], u2h((B).x)); D[5] = __hadd2(D[5], u2h((B).y)); \
    D[6] = __hadd2(D[6], u2h((B).z)); D[7] = __hadd2(D[7], u2h((B).w));

    // ---- phase 2: sparse gather, 8 neighbors/iter, 16 b128 reads in flight ----
    for (int u = 0; u < 4; ++u) {
        const int j = t + u * TB;
        const int4* ir = (const int4*)(idx + (size_t)j * CAP);
        // rolling prefetch of next u's metadata (hidden under this u's gather)
        int ncc = 0; int4 nk0 = ka, nk1 = kb;
        if (u < 3) {
            const int jn = j + TB;
            const int4* irn = (const int4*)(idx + (size_t)jn * CAP);
            ncc = cnt8[jn];
            nk0 = irn[0];
            nk1 = irn[1];
        }
        __half2 d0[8], d1[8], d2[8], d3[8];   // 4 independent chains
        const __half2 z = u2h(0u);
#pragma unroll
        for (int r = 0; r < 8; ++r) { d0[r] = z; d1[r] = z; d2[r] = z; d3[r] = z; }

        for (int c = 0; c < cc; ++c) {
            int4 pa = ka, pb = kb;
            if (c + 1 < cc) { pa = ir[2 * c + 2]; pb = ir[2 * c + 3]; }
            const uint4 ax = sA[ka.x], bx = sB[ka.x];
            const uint4 ay = sA[ka.y], by = sB[ka.y];
            const uint4 az = sA[ka.z], bz = sB[ka.z];
            const uint4 aw = sA[ka.w], bw = sB[ka.w];
            const uint4 ex = sA[kb.x], fx = sB[kb.x];
            const uint4 ey = sA[kb.y], fy = sB[kb.y];
            const uint4 ez = sA[kb.z], fz = sB[kb.z];
            const uint4 ew = sA[kb.w], fw = sB[kb.w];
            ACC(d0, ax, bx)
            ACC(d1, ay, by)
            ACC(d0, az, bz)
            ACC(d1, aw, bw)
            ACC(d2, ex, fx)
            ACC(d3, ey, fy)
            ACC(d2, ez, fz)
            ACC(d3, ew, fw)
            ka = pa; kb = pb;
        }
        const uint4 na4 = sA[j], nb4 = sB[j];
        const unsigned int nu[8] = {na4.x, na4.y, na4.z, na4.w,
                                    nb4.x, nb4.y, nb4.z, nb4.w};
#pragma unroll
        for (int i = 0; i < 8; ++i) {
            const __half2 dd = __hadd2(__hadd2(d0[i], d1[i]), __hadd2(d2[i], d3[i]));
            const __half2 nn = u2h(nu[i]);
            out[(size_t)(i0 + 2 * i + 0) * N + j] =
                __low2float(nn)  * __builtin_amdgcn_rcpf(__low2float(dd));
            out[(size_t)(i0 + 2 * i + 1) * N + j] =
                __high2float(nn) * __builtin_amdgcn_rcpf(__high2float(dd));
        }
        cc = ncc; ka = nk0; kb = nk1;
    }
#undef ACC
}

extern "C" void kernel_launch(void* const* d_in, const int* in_sizes, int n_in,
                              void* d_out, int out_size, void* d_ws, size_t ws_size,
                              hipStream_t stream) {
    const float* f  = (const float*)d_in[0];   // [SIZE, N]
    const float* nb = (const float*)d_in[1];   // [N, N]
    const float* wq = (const float*)d_in[2];   // [SIZE]
    const float* wk = (const float*)d_in[3];   // [SIZE]
    float* out = (float*)d_out;                // [N, N]

    // workspace: cnt8 (N int) | idx (N*CAP int) | Af (512K f16) | Bf (512K f16) ~= 4.1 MB
    int*      cnt8 = (int*)d_ws;
    int*      idx  = cnt8 + N;
    _Float16* Af   = (_Float16*)(idx + (size_t)N * CAP);
    _Float16* Bf   = Af + (size_t)256 * 4 * 64 * 8;

    setup<<<N + 256, 256, 0, stream>>>(nb, f, wq, wk, cnt8, idx, Af, Bf);
    fused<<<N / RB, TB, 0, stream>>>(Af, Bf, cnt8, idx, out);
}